// Round 4
// baseline (544.198 us; speedup 1.0000x reference)
//
#include <hip/hip_runtime.h>
#include <hip/hip_bf16.h>
#include <cstdint>
#include <cstddef>

// minLSTM: out = exp(heinsen_scan(log_f, log_i + log_g(h))), [h,f,i] = x @ W
// B=4 S=8192 D=1024. GEMM bf16 MFMA (fp32 accum) -> bf16 hW; linear-domain
// chunked EMA scan (F=sigmoid(-d), I=1-F) with log-domain cross-chunk scan.
// R8: (a) GEMM barriers 8->2 per K-tile. Only two sync points are needed:
//     after ph1's VMC(4) (A1,B1(t) visibility for ph2/ph3 reads) and after
//     ph4's VMC(4) (A0,B0(t+1) visibility for next ph1). All WAR hazards are
//     covered by >=1 barrier + per-wave lgkmcnt-before-MFMA ordering.
//     Waves now drift through ph2/ph3 -> MFMA of one wave covers ds_reads of
//     another (setprio arbitrates).
// (b) scans: CHUNKS 256->512 (CLEN=16) -> 2048 blocks, 24 waves/CU (was 16),
//     half the serial chain per block; attacks exposed load latency.

#define BB 4
#define SS 8192
#define DD 1024
#define MM 32768   // B*S
#define KK 1024    // D
#define NN 3072    // 3*D
#define CHUNKS 512
#define CLEN 16    // SS / CHUNKS
#define NCH 4096   // B*D channels
#define NT 16      // KK / 64 K-tiles

typedef __bf16 bf16;
typedef __bf16 bf16x2 __attribute__((ext_vector_type(2)));
typedef __bf16 bf16x4 __attribute__((ext_vector_type(4)));
typedef __bf16 bf16x8 __attribute__((ext_vector_type(8)));
typedef float f32x4 __attribute__((ext_vector_type(4)));

// ---- async global->LDS, 16B per lane (wave-uniform LDS base + lane*16) ----
__device__ __forceinline__ void gload16(const bf16* g, bf16* l) {
  __builtin_amdgcn_global_load_lds(
      (const __attribute__((address_space(1))) unsigned int*)(const void*)g,
      (__attribute__((address_space(3))) unsigned int*)(void*)l,
      16, 0, 0);
}

// ---- linear-domain gate evaluation ----------------------------------------
// F = sigmoid(-(sp(-f)-sp(-i))) = (1+e^-i)/(2+e^-f+e^-i); I = 1-F.
// IG = I * g(h), g(h) = h>=0 ? h+0.5 : sigmoid(h).
__device__ __forceinline__ void gate2(float h, float f, float i,
                                      float& F, float& IG) {
  float P = __expf(fminf(-f, 80.f));
  float Q = __expf(fminf(-i, 80.f));
  float rZ = __builtin_amdgcn_rcpf(2.f + P + Q);
  float eh = __expf(fminf(-h, 80.f));
  float gh = (h >= 0.f) ? (h + 0.5f) : __builtin_amdgcn_rcpf(1.f + eh);
  F = (1.f + Q) * rZ;
  IG = (1.f + P) * gh * rZ;
}

// ---- log-domain combine for the cross-chunk scan (scan2) ------------------
__device__ __forceinline__ float laddexp(float a, float b) {
  float m = fmaxf(a, b);
  return m + __logf(1.f + __expf(fminf(a, b) - m));
}
__device__ __forceinline__ void comb(float& A, float& V, float Ac, float Vc) {
  V = laddexp(V + Ac, Vc);
  A += Ac;
}

// ---- convert x fp32 -> bf16 (vectorized) ----
__global__ __launch_bounds__(256) void k_cvt_x(const float4* __restrict__ x,
                                               bf16x4* __restrict__ xb) {
  int i = blockIdx.x * 256 + threadIdx.x;
  float4 v = x[i];
  bf16x4 o;
  o[0] = (bf16)v.x; o[1] = (bf16)v.y; o[2] = (bf16)v.z; o[3] = (bf16)v.w;
  xb[i] = o;
}

// ---- convert + transpose W [K,N] fp32 -> Wt [N,K] bf16 (LDS 32x32 tile) ----
__global__ __launch_bounds__(256) void k_cvt_wt(const float* __restrict__ W,
                                                bf16* __restrict__ Wt) {
  __shared__ float tile[32][33];
  int n0 = blockIdx.x * 32, k0 = blockIdx.y * 32;
  int tx = threadIdx.x, ty = threadIdx.y;  // (32, 8)
#pragma unroll
  for (int i = 0; i < 32; i += 8)
    tile[ty + i][tx] = W[(size_t)(k0 + ty + i) * NN + n0 + tx];
  __syncthreads();
#pragma unroll
  for (int i = 0; i < 32; i += 8)
    Wt[(size_t)(n0 + ty + i) * KK + k0 + tx] = (bf16)tile[tx][ty + i];
}

// ---- bf16 GEMM, C[m][n] = sum_k A[m][k]*Bt[n][k] --------------------------
// 256x256 tile, BK=64, 8 waves (2Mx4N), counted vmcnt, LDS XOR-swizzle,
// dual B-frag sets, 2 barriers per K-tile.
__global__ __launch_bounds__(512, 2) void k_gemm(const bf16* __restrict__ A,
                                                 const bf16* __restrict__ Bt,
                                                 bf16* __restrict__ C) {
  __shared__ __align__(16) bf16 sm[65536];  // 128 KiB
  const int tid = threadIdx.x;
  const int lane = tid & 63;
  const int w = tid >> 6;          // 0..7
  const int wm = w >> 2;           // 0..1 (M)
  const int wn = w & 3;            // 0..3 (N)
  const int c16 = lane & 15;
  const int l4 = lane >> 4;

  // XCD-aware bijective swizzle: 1536 blocks = 8 XCD * 192; nT fast inside
  // a chunk so consecutive same-XCD blocks reuse the A panel in L2.
  int bid = blockIdx.x;
  int swz = (bid & 7) * 192 + (bid >> 3);
  int mT = swz / 12;
  int nT = swz - mT * 12;
  const int mBase = mT * 256, nBase = nT * 256;

  // staging: thread covers LDS linear slot (row = tid>>3 (+64*L +128*half),
  // slot = tid&7); global source column pre-swizzled (inverse of read XOR).
  const int sr = tid >> 3;                       // 0..63
  const int scol = ((tid & 7) ^ (sr & 7)) * 8;   // swizzled k-col (elems)
  const bf16* gA = A + (size_t)(mBase + sr) * KK + scol;
  const bf16* gB = Bt + (size_t)(nBase + sr) * KK + scol;
  const int ld = tid * 8;                        // linear LDS dest (elems)

  // ds_read: addr = region + row*64 + ((slot ^ (row&7))*8); row&7 == c16&7
  const int sw8 = c16 & 7;
  const int sx0 = (l4 ^ sw8) * 8;          // ksub=0 (slots 0..3)
  const int sx1 = ((l4 + 4) ^ sw8) * 8;    // ksub=1 (slots 4..7)
  const int aRow = (wm * 64 + c16) * 64;   // + qm*8192 + mi*1024
  const int bRow = (wn * 32 + c16) * 64;   // + qn*8192 + ni*1024

  f32x4 acc[2][2][4][2];  // [qm][qn][mi][ni]
#pragma unroll
  for (int a = 0; a < 2; ++a)
#pragma unroll
    for (int b2 = 0; b2 < 2; ++b2)
#pragma unroll
      for (int m = 0; m < 4; ++m)
#pragma unroll
        for (int n = 0; n < 2; ++n)
          acc[a][b2][m][n] = (f32x4){0.f, 0.f, 0.f, 0.f};

#define STGA(h, L, bo, ko) \
  gload16(gA + (h) * 131072 + (L) * 65536 + (ko), \
          sm + (bo) + (h) * 8192 + (L) * 4096 + ld)
#define STGB(h, L, bo, ko) \
  gload16(gB + (h) * 131072 + (L) * 65536 + (ko), \
          sm + (bo) + 16384 + (h) * 8192 + (L) * 4096 + ld)
#define LDA(qm, AF)                                                     \
  _Pragma("unroll") for (int mi = 0; mi < 4; ++mi) {                    \
    const bf16* p_ = sm + buf + (qm) * 8192 + aRow + mi * 1024;         \
    AF[mi][0] = *(const bf16x8*)(p_ + sx0);                             \
    AF[mi][1] = *(const bf16x8*)(p_ + sx1);                             \
  }
#define LDB(qn, BF)                                                     \
  _Pragma("unroll") for (int ni = 0; ni < 2; ++ni) {                    \
    const bf16* p_ = sm + buf + 16384 + (qn) * 8192 + bRow + ni * 1024; \
    BF[ni][0] = *(const bf16x8*)(p_ + sx0);                             \
    BF[ni][1] = *(const bf16x8*)(p_ + sx1);                             \
  }
#define MFMAQ(qm, qn, AF, BF)                                             \
  __builtin_amdgcn_s_setprio(1);                                          \
  _Pragma("unroll") for (int mi = 0; mi < 4; ++mi)                        \
  _Pragma("unroll") for (int ni = 0; ni < 2; ++ni) {                      \
    acc[qm][qn][mi][ni] = __builtin_amdgcn_mfma_f32_16x16x32_bf16(        \
        AF[mi][0], BF[ni][0], acc[qm][qn][mi][ni], 0, 0, 0);              \
    acc[qm][qn][mi][ni] = __builtin_amdgcn_mfma_f32_16x16x32_bf16(        \
        AF[mi][1], BF[ni][1], acc[qm][qn][mi][ni], 0, 0, 0);              \
  }                                                                       \
  __builtin_amdgcn_s_setprio(0);
#define BAR asm volatile("s_barrier" ::: "memory")
#define VMC(n) asm volatile("s_waitcnt vmcnt(" #n ")" ::: "memory")

  // prologue: stage K-tile 0 into buffer 0 (issue order A0,B0,A1,B1)
  STGA(0, 0, 0, 0); STGA(0, 1, 0, 0); STGB(0, 0, 0, 0); STGB(0, 1, 0, 0);
  STGA(1, 0, 0, 0); STGA(1, 1, 0, 0); STGB(1, 0, 0, 0); STGB(1, 1, 0, 0);
  VMC(4);  // A0,B0 resident; A1,B1 may fly
  BAR;

  bf16x8 afr[4][2], bfr0[2][2], bfr1[2][2];

  for (int t = 0; t < NT - 1; ++t) {
    const int buf = (t & 1) << 15;
    const int nb = buf ^ 32768;
    const int ko = (t + 1) * 64;
    // ph1: Q(0,0) — reads A0 (afr), B0 (bfr0); stage A0,B0(t+1)
    LDA(0, afr); LDB(0, bfr0);
    STGA(0, 0, nb, ko); STGA(0, 1, nb, ko);
    STGB(0, 0, nb, ko); STGB(0, 1, nb, ko);
    VMC(4);  // retires A1,B1(t); leaves A0,B0(t+1) in flight
    BAR;     // -> A1,B1(t) visible to all waves before ph2/ph3 reads
    MFMAQ(0, 0, afr, bfr0);
    // ph2: Q(0,1) — reads B1 (bfr1); afr kept; stage A1(t+1). no barrier.
    LDB(1, bfr1);
    STGA(1, 0, nb, ko); STGA(1, 1, nb, ko);
    MFMAQ(0, 1, afr, bfr1);
    // ph3: Q(1,1) — reads A1 (afr overwrite); bfr1 kept; stage B1(t+1).
    LDA(1, afr);
    STGB(1, 0, nb, ko); STGB(1, 1, nb, ko);
    MFMAQ(1, 1, afr, bfr1);
    // ph4: Q(1,0) — NO ds reads (afr=A1, bfr0=B0 both live)
    VMC(4);  // retires A0,B0(t+1); leaves A1,B1(t+1) in flight
    BAR;     // -> A0,B0(t+1) visible before next ph1 reads
    MFMAQ(1, 0, afr, bfr0);
  }
  {  // peeled last K-tile (t = NT-1, buf = 32768), no staging
    const int buf = 32768;
    LDA(0, afr); LDB(0, bfr0);
    VMC(0);  // drain: A1,B1 of last tile
    BAR;
    MFMAQ(0, 0, afr, bfr0);
    LDB(1, bfr1);
    MFMAQ(0, 1, afr, bfr1);
    LDA(1, afr);
    MFMAQ(1, 1, afr, bfr1);
    MFMAQ(1, 0, afr, bfr0);
  }

  // Epilogue: LDS-transpose (swizzled, stride 256) then coalesced 16B stores.
  // C/D layout: col=lane&15 (N), row=(lane>>4)*4+reg (M) [m89-verified].
  __syncthreads();
  const int rq = l4 * 4;
#pragma unroll
  for (int qm = 0; qm < 2; ++qm)
#pragma unroll
    for (int qn = 0; qn < 2; ++qn)
#pragma unroll
      for (int mi = 0; mi < 4; ++mi)
#pragma unroll
        for (int ni = 0; ni < 2; ++ni)
#pragma unroll
          for (int r = 0; r < 4; ++r) {
            int row = qm * 128 + wm * 64 + mi * 16 + rq + r;
            int col = (qn * 128 + wn * 32 + ni * 16 + c16) ^ ((row & 7) << 3);
            sm[row * 256 + col] = (bf16)acc[qm][qn][mi][ni][r];
          }
  __syncthreads();
#pragma unroll
  for (int p = 0; p < 16; ++p) {
    int row = p * 16 + (tid >> 5);
    int colL = (tid & 31) * 8;                    // logical col
    int col = colL ^ ((row & 7) << 3);            // swizzled LDS col
    bf16x8 v = *(const bf16x8*)(sm + row * 256 + col);
    *(bf16x8*)(C + (size_t)(mBase + row) * NN + nBase + colL) = v;
  }
#undef STGA
#undef STGB
#undef LDA
#undef LDB
#undef MFMAQ
#undef BAR
#undef VMC
}

// ---- scan phase 1: per-chunk aggregate, linear domain, 4 ch/thread --------
// agg layout: [channel][chunk] (channel = b*DD + d), values in LOG domain.
__global__ __launch_bounds__(256, 6) void k_scan1(const bf16* __restrict__ hW,
                                                  float2* __restrict__ agg) {
  const int d0 = threadIdx.x * 4;
  const int b = blockIdx.y, c = blockIdx.z;
  const bf16* p = hW + (size_t)(b * SS + c * CLEN) * NN + d0;
  float Fp[4] = {1.f, 1.f, 1.f, 1.f};
  float v[4] = {0.f, 0.f, 0.f, 0.f};
  bf16x4 hh = *(const bf16x4*)(p);
  bf16x4 ff = *(const bf16x4*)(p + DD);
  bf16x4 ii = *(const bf16x4*)(p + 2 * DD);
#pragma unroll 4
  for (int j = 0; j < CLEN - 1; ++j) {
    p += NN;
    bf16x4 hn = *(const bf16x4*)(p);
    bf16x4 fn = *(const bf16x4*)(p + DD);
    bf16x4 in2 = *(const bf16x4*)(p + 2 * DD);
#pragma unroll
    for (int e = 0; e < 4; ++e) {
      float F, IG;
      gate2((float)hh[e], (float)ff[e], (float)ii[e], F, IG);
      v[e] = fmaf(v[e], F, IG);
      Fp[e] *= F;
    }
    hh = hn; ff = fn; ii = in2;
  }
#pragma unroll
  for (int e = 0; e < 4; ++e) {
    float F, IG;
    gate2((float)hh[e], (float)ff[e], (float)ii[e], F, IG);
    v[e] = fmaf(v[e], F, IG);
    Fp[e] *= F;
  }
  const size_t ch = (size_t)b * DD + d0;
#pragma unroll
  for (int e = 0; e < 4; ++e)
    agg[(ch + e) * CHUNKS + c] =
        make_float2(__logf(fmaxf(Fp[e], 1e-37f)), __logf(fmaxf(v[e], 1e-37f)));
}

// ---- scan phase 2: wave-parallel exclusive scan over chunks (log domain) --
// One wave per channel; lane holds 8 chunk aggregates (4 float4); shfl scan.
__global__ __launch_bounds__(256) void k_scan2(const float2* __restrict__ agg,
                                               float2* __restrict__ pre) {
  const int ch = blockIdx.x * 4 + (threadIdx.x >> 6);
  const int lane = threadIdx.x & 63;
  const float4* src = (const float4*)(agg + (size_t)ch * CHUNKS);
  float4 v[4];
#pragma unroll
  for (int q = 0; q < 4; ++q) v[q] = src[lane * 4 + q];
  // lane-local fold (8 chunks)
  float A = v[0].x, V = v[0].y;
  comb(A, V, v[0].z, v[0].w);
#pragma unroll
  for (int q = 1; q < 4; ++q) {
    comb(A, V, v[q].x, v[q].y);
    comb(A, V, v[q].z, v[q].w);
  }
  // inclusive wave scan of lane aggregates
#pragma unroll
  for (int off = 1; off < 64; off <<= 1) {
    float Ao = __shfl_up(A, off);
    float Vo = __shfl_up(V, off);
    if (lane >= off) {
      V = laddexp(Vo + A, V);
      A = Ao + A;
    }
  }
  // exclusive lane prefix
  float exA = __shfl_up(A, 1);
  float exV = __shfl_up(V, 1);
  if (lane == 0) { exA = 0.f; exV = -1e30f; }
  // produce exclusive per-chunk prefixes
  float4* dst = (float4*)(pre + (size_t)ch * CHUNKS);
#pragma unroll
  for (int q = 0; q < 4; ++q) {
    float4 o;
    o.x = exA; o.y = exV;
    comb(exA, exV, v[q].x, v[q].y);
    o.z = exA; o.w = exV;
    comb(exA, exV, v[q].z, v[q].w);
    dst[lane * 4 + q] = o;
  }
}

// ---- scan phase 3: re-run chunk in linear domain; out IS the state --------
__global__ __launch_bounds__(256, 6) void k_scan3(const bf16* __restrict__ hW,
                                                  const float2* __restrict__ pre,
                                                  float* __restrict__ out) {
  const int d0 = threadIdx.x * 4;
  const int b = blockIdx.y, c = blockIdx.z;
  const bf16* p = hW + (size_t)(b * SS + c * CLEN) * NN + d0;
  float* o = out + (size_t)(b * SS + c * CLEN) * DD + d0;
  const size_t ch = (size_t)b * DD + d0;
  float v[4];
#pragma unroll
  for (int e = 0; e < 4; ++e)
    v[e] = __expf(pre[(ch + e) * CHUNKS + c].y);  // exp(-1e30) = 0 for c=0
  bf16x4 hh = *(const bf16x4*)(p);
  bf16x4 ff = *(const bf16x4*)(p + DD);
  bf16x4 ii = *(const bf16x4*)(p + 2 * DD);
#pragma unroll 4
  for (int j = 0; j < CLEN - 1; ++j) {
    p += NN;
    bf16x4 hn = *(const bf16x4*)(p);
    bf16x4 fn = *(const bf16x4*)(p + DD);
    bf16x4 in2 = *(const bf16x4*)(p + 2 * DD);
    float4 ov;
#pragma unroll
    for (int e = 0; e < 4; ++e) {
      float F, IG;
      gate2((float)hh[e], (float)ff[e], (float)ii[e], F, IG);
      v[e] = fmaf(v[e], F, IG);
    }
    ov.x = v[0]; ov.y = v[1]; ov.z = v[2]; ov.w = v[3];
    *(float4*)o = ov;
    o += DD;
    hh = hn; ff = fn; ii = in2;
  }
  float4 ov;
#pragma unroll
  for (int e = 0; e < 4; ++e) {
    float F, IG;
    gate2((float)hh[e], (float)ff[e], (float)ii[e], F, IG);
    v[e] = fmaf(v[e], F, IG);
  }
  ov.x = v[0]; ov.y = v[1]; ov.z = v[2]; ov.w = v[3];
  *(float4*)o = ov;
}

extern "C" void kernel_launch(void* const* d_in, const int* in_sizes, int n_in,
                              void* d_out, int out_size, void* d_ws,
                              size_t ws_size, hipStream_t stream) {
  const float* x = (const float*)d_in[0];
  const float* W = (const float*)d_in[1];
  float* out = (float*)d_out;
  char* ws = (char*)d_ws;

  // workspace layout: [Wt 6MB][xb 64MB][hW 192MB]; agg/pre (16MB each)
  // overlay the xb region, which is dead after the GEMM completes.
  const size_t wtB = (size_t)NN * KK * 2;   //  6,291,456
  const size_t xbB = (size_t)MM * KK * 2;   // 67,108,864
  const size_t aggB = (size_t)CHUNKS * NCH * sizeof(float2);  // 16 MiB
  bf16* Wt = (bf16*)ws;
  bf16* xb = (bf16*)(ws + wtB);
  bf16* hW = (bf16*)(ws + wtB + xbB);
  float2* agg = (float2*)(ws + wtB);          // overlays xb (dead post-GEMM)
  float2* pre = (float2*)(ws + wtB + aggB);

  k_cvt_wt<<<dim3(NN / 32, KK / 32), dim3(32, 8), 0, stream>>>(W, Wt);
  k_cvt_x<<<dim3(MM * KK / 4 / 256), dim3(256), 0, stream>>>((const float4*)x,
                                                             (bf16x4*)xb);
  k_gemm<<<dim3((NN / 256) * (MM / 256)), 512, 0, stream>>>(xb, Wt, hW);
  k_scan1<<<dim3(1, BB, CHUNKS), 256, 0, stream>>>(hW, agg);
  k_scan2<<<dim3(NCH / 4), 256, 0, stream>>>(agg, pre);
  k_scan3<<<dim3(1, BB, CHUNKS), 256, 0, stream>>>(hW, pre, out);
}

// Round 5
// 528.162 us; speedup vs baseline: 1.0304x; 1.0304x over previous
//
#include <hip/hip_runtime.h>
#include <hip/hip_bf16.h>
#include <cstdint>
#include <cstddef>

// minLSTM: out = exp(heinsen_scan(log_f, log_i + log_g(h))), [h,f,i] = x @ W
// B=4 S=8192 D=1024. GEMM bf16 MFMA (fp32 accum) -> bf16 hW; linear-domain
// chunked EMA scan (F=sigmoid(-d), I=1-F) with log-domain cross-chunk scan.
// R9: (a) revert CHUNKS to 256 (512 regressed +29us: tail quantization +
//     per-block fixed cost). (b) gate2 in base-2 with native v_exp_f32 via
//     __builtin_amdgcn_exp2f (__has_builtin-guarded). (c) scans: drop the
//     (256,6) VGPR cap (grid-limited to 4 blocks/CU anyway) + explicit
//     2-row-deep load prefetch rotation. GEMM: R8's 2-barrier schedule kept.

#define BB 4
#define SS 8192
#define DD 1024
#define MM 32768   // B*S
#define KK 1024    // D
#define NN 3072    // 3*D
#define CHUNKS 256
#define CLEN 32    // SS / CHUNKS
#define NCH 4096   // B*D channels
#define NT 16      // KK / 64 K-tiles

typedef __bf16 bf16;
typedef __bf16 bf16x2 __attribute__((ext_vector_type(2)));
typedef __bf16 bf16x4 __attribute__((ext_vector_type(4)));
typedef __bf16 bf16x8 __attribute__((ext_vector_type(8)));
typedef float f32x4 __attribute__((ext_vector_type(4)));

// ---- async global->LDS, 16B per lane (wave-uniform LDS base + lane*16) ----
__device__ __forceinline__ void gload16(const bf16* g, bf16* l) {
  __builtin_amdgcn_global_load_lds(
      (const __attribute__((address_space(1))) unsigned int*)(const void*)g,
      (__attribute__((address_space(3))) unsigned int*)(void*)l,
      16, 0, 0);
}

// ---- native 2^x (hedged: fall back to __expf if builtin name is absent) ---
#if __has_builtin(__builtin_amdgcn_exp2f)
#define EXP2(x) __builtin_amdgcn_exp2f(x)
#else
#define EXP2(x) __expf((x) * 0.69314718056f)
#endif

// ---- linear-domain gate evaluation (base-2) -------------------------------
// F = sigmoid(-(sp(-f)-sp(-i))) = (1+e^-i)/(2+e^-f+e^-i); I = 1-F.
// IG = I * g(h), g(h) = h>=0 ? h+0.5 : sigmoid(h).
// Clamp exp2 args at 60: P<=2^60 keeps rZ normal; IG -> (P)(gh)(1/P) = gh ok.
__device__ __forceinline__ void gate2(float h, float f, float i,
                                      float& F, float& IG) {
  const float NL2E = -1.44269504089f;  // -log2(e)
  float P = EXP2(fminf(f * NL2E, 60.f));
  float Q = EXP2(fminf(i * NL2E, 60.f));
  float H = EXP2(fminf(h * NL2E, 60.f));
  float rZ = __builtin_amdgcn_rcpf(2.f + P + Q);
  float gh = (h >= 0.f) ? (h + 0.5f) : __builtin_amdgcn_rcpf(1.f + H);
  F = (1.f + Q) * rZ;
  IG = (1.f + P) * gh * rZ;
}

// ---- log-domain combine for the cross-chunk scan (scan2) ------------------
__device__ __forceinline__ float laddexp(float a, float b) {
  float m = fmaxf(a, b);
  return m + __logf(1.f + __expf(fminf(a, b) - m));
}
__device__ __forceinline__ void comb(float& A, float& V, float Ac, float Vc) {
  V = laddexp(V + Ac, Vc);
  A += Ac;
}

// ---- convert x fp32 -> bf16 (vectorized) ----
__global__ __launch_bounds__(256) void k_cvt_x(const float4* __restrict__ x,
                                               bf16x4* __restrict__ xb) {
  int i = blockIdx.x * 256 + threadIdx.x;
  float4 v = x[i];
  bf16x4 o;
  o[0] = (bf16)v.x; o[1] = (bf16)v.y; o[2] = (bf16)v.z; o[3] = (bf16)v.w;
  xb[i] = o;
}

// ---- convert + transpose W [K,N] fp32 -> Wt [N,K] bf16 (LDS 32x32 tile) ----
__global__ __launch_bounds__(256) void k_cvt_wt(const float* __restrict__ W,
                                                bf16* __restrict__ Wt) {
  __shared__ float tile[32][33];
  int n0 = blockIdx.x * 32, k0 = blockIdx.y * 32;
  int tx = threadIdx.x, ty = threadIdx.y;  // (32, 8)
#pragma unroll
  for (int i = 0; i < 32; i += 8)
    tile[ty + i][tx] = W[(size_t)(k0 + ty + i) * NN + n0 + tx];
  __syncthreads();
#pragma unroll
  for (int i = 0; i < 32; i += 8)
    Wt[(size_t)(n0 + ty + i) * KK + k0 + tx] = (bf16)tile[tx][ty + i];
}

// ---- bf16 GEMM, C[m][n] = sum_k A[m][k]*Bt[n][k] --------------------------
// 256x256 tile, BK=64, 8 waves (2Mx4N), counted vmcnt, LDS XOR-swizzle,
// dual B-frag sets, 2 barriers per K-tile. (R8, unchanged)
__global__ __launch_bounds__(512, 2) void k_gemm(const bf16* __restrict__ A,
                                                 const bf16* __restrict__ Bt,
                                                 bf16* __restrict__ C) {
  __shared__ __align__(16) bf16 sm[65536];  // 128 KiB
  const int tid = threadIdx.x;
  const int lane = tid & 63;
  const int w = tid >> 6;          // 0..7
  const int wm = w >> 2;           // 0..1 (M)
  const int wn = w & 3;            // 0..3 (N)
  const int c16 = lane & 15;
  const int l4 = lane >> 4;

  // XCD-aware bijective swizzle: 1536 blocks = 8 XCD * 192; nT fast inside
  // a chunk so consecutive same-XCD blocks reuse the A panel in L2.
  int bid = blockIdx.x;
  int swz = (bid & 7) * 192 + (bid >> 3);
  int mT = swz / 12;
  int nT = swz - mT * 12;
  const int mBase = mT * 256, nBase = nT * 256;

  // staging: thread covers LDS linear slot (row = tid>>3 (+64*L +128*half),
  // slot = tid&7); global source column pre-swizzled (inverse of read XOR).
  const int sr = tid >> 3;                       // 0..63
  const int scol = ((tid & 7) ^ (sr & 7)) * 8;   // swizzled k-col (elems)
  const bf16* gA = A + (size_t)(mBase + sr) * KK + scol;
  const bf16* gB = Bt + (size_t)(nBase + sr) * KK + scol;
  const int ld = tid * 8;                        // linear LDS dest (elems)

  // ds_read: addr = region + row*64 + ((slot ^ (row&7))*8); row&7 == c16&7
  const int sw8 = c16 & 7;
  const int sx0 = (l4 ^ sw8) * 8;          // ksub=0 (slots 0..3)
  const int sx1 = ((l4 + 4) ^ sw8) * 8;    // ksub=1 (slots 4..7)
  const int aRow = (wm * 64 + c16) * 64;   // + qm*8192 + mi*1024
  const int bRow = (wn * 32 + c16) * 64;   // + qn*8192 + ni*1024

  f32x4 acc[2][2][4][2];  // [qm][qn][mi][ni]
#pragma unroll
  for (int a = 0; a < 2; ++a)
#pragma unroll
    for (int b2 = 0; b2 < 2; ++b2)
#pragma unroll
      for (int m = 0; m < 4; ++m)
#pragma unroll
        for (int n = 0; n < 2; ++n)
          acc[a][b2][m][n] = (f32x4){0.f, 0.f, 0.f, 0.f};

#define STGA(h, L, bo, ko) \
  gload16(gA + (h) * 131072 + (L) * 65536 + (ko), \
          sm + (bo) + (h) * 8192 + (L) * 4096 + ld)
#define STGB(h, L, bo, ko) \
  gload16(gB + (h) * 131072 + (L) * 65536 + (ko), \
          sm + (bo) + 16384 + (h) * 8192 + (L) * 4096 + ld)
#define LDA(qm, AF)                                                     \
  _Pragma("unroll") for (int mi = 0; mi < 4; ++mi) {                    \
    const bf16* p_ = sm + buf + (qm) * 8192 + aRow + mi * 1024;         \
    AF[mi][0] = *(const bf16x8*)(p_ + sx0);                             \
    AF[mi][1] = *(const bf16x8*)(p_ + sx1);                             \
  }
#define LDB(qn, BF)                                                     \
  _Pragma("unroll") for (int ni = 0; ni < 2; ++ni) {                    \
    const bf16* p_ = sm + buf + 16384 + (qn) * 8192 + bRow + ni * 1024; \
    BF[ni][0] = *(const bf16x8*)(p_ + sx0);                             \
    BF[ni][1] = *(const bf16x8*)(p_ + sx1);                             \
  }
#define MFMAQ(qm, qn, AF, BF)                                             \
  __builtin_amdgcn_s_setprio(1);                                          \
  _Pragma("unroll") for (int mi = 0; mi < 4; ++mi)                        \
  _Pragma("unroll") for (int ni = 0; ni < 2; ++ni) {                      \
    acc[qm][qn][mi][ni] = __builtin_amdgcn_mfma_f32_16x16x32_bf16(        \
        AF[mi][0], BF[ni][0], acc[qm][qn][mi][ni], 0, 0, 0);              \
    acc[qm][qn][mi][ni] = __builtin_amdgcn_mfma_f32_16x16x32_bf16(        \
        AF[mi][1], BF[ni][1], acc[qm][qn][mi][ni], 0, 0, 0);              \
  }                                                                       \
  __builtin_amdgcn_s_setprio(0);
#define BAR asm volatile("s_barrier" ::: "memory")
#define VMC(n) asm volatile("s_waitcnt vmcnt(" #n ")" ::: "memory")

  // prologue: stage K-tile 0 into buffer 0 (issue order A0,B0,A1,B1)
  STGA(0, 0, 0, 0); STGA(0, 1, 0, 0); STGB(0, 0, 0, 0); STGB(0, 1, 0, 0);
  STGA(1, 0, 0, 0); STGA(1, 1, 0, 0); STGB(1, 0, 0, 0); STGB(1, 1, 0, 0);
  VMC(4);  // A0,B0 resident; A1,B1 may fly
  BAR;

  bf16x8 afr[4][2], bfr0[2][2], bfr1[2][2];

  for (int t = 0; t < NT - 1; ++t) {
    const int buf = (t & 1) << 15;
    const int nb = buf ^ 32768;
    const int ko = (t + 1) * 64;
    // ph1: Q(0,0) — reads A0 (afr), B0 (bfr0); stage A0,B0(t+1)
    LDA(0, afr); LDB(0, bfr0);
    STGA(0, 0, nb, ko); STGA(0, 1, nb, ko);
    STGB(0, 0, nb, ko); STGB(0, 1, nb, ko);
    VMC(4);  // retires A1,B1(t); leaves A0,B0(t+1) in flight
    BAR;     // -> A1,B1(t) visible to all waves before ph2/ph3 reads
    MFMAQ(0, 0, afr, bfr0);
    // ph2: Q(0,1) — reads B1 (bfr1); afr kept; stage A1(t+1). no barrier.
    LDB(1, bfr1);
    STGA(1, 0, nb, ko); STGA(1, 1, nb, ko);
    MFMAQ(0, 1, afr, bfr1);
    // ph3: Q(1,1) — reads A1 (afr overwrite); bfr1 kept; stage B1(t+1).
    LDA(1, afr);
    STGB(1, 0, nb, ko); STGB(1, 1, nb, ko);
    MFMAQ(1, 1, afr, bfr1);
    // ph4: Q(1,0) — NO ds reads (afr=A1, bfr0=B0 both live)
    VMC(4);  // retires A0,B0(t+1); leaves A1,B1(t+1) in flight
    BAR;     // -> A0,B0(t+1) visible before next ph1 reads
    MFMAQ(1, 0, afr, bfr0);
  }
  {  // peeled last K-tile (t = NT-1, buf = 32768), no staging
    const int buf = 32768;
    LDA(0, afr); LDB(0, bfr0);
    VMC(0);  // drain: A1,B1 of last tile
    BAR;
    MFMAQ(0, 0, afr, bfr0);
    LDB(1, bfr1);
    MFMAQ(0, 1, afr, bfr1);
    LDA(1, afr);
    MFMAQ(1, 1, afr, bfr1);
    MFMAQ(1, 0, afr, bfr0);
  }

  // Epilogue: LDS-transpose (swizzled, stride 256) then coalesced 16B stores.
  // C/D layout: col=lane&15 (N), row=(lane>>4)*4+reg (M) [m89-verified].
  __syncthreads();
  const int rq = l4 * 4;
#pragma unroll
  for (int qm = 0; qm < 2; ++qm)
#pragma unroll
    for (int qn = 0; qn < 2; ++qn)
#pragma unroll
      for (int mi = 0; mi < 4; ++mi)
#pragma unroll
        for (int ni = 0; ni < 2; ++ni)
#pragma unroll
          for (int r = 0; r < 4; ++r) {
            int row = qm * 128 + wm * 64 + mi * 16 + rq + r;
            int col = (qn * 128 + wn * 32 + ni * 16 + c16) ^ ((row & 7) << 3);
            sm[row * 256 + col] = (bf16)acc[qm][qn][mi][ni][r];
          }
  __syncthreads();
#pragma unroll
  for (int p = 0; p < 16; ++p) {
    int row = p * 16 + (tid >> 5);
    int colL = (tid & 31) * 8;                    // logical col
    int col = colL ^ ((row & 7) << 3);            // swizzled LDS col
    bf16x8 v = *(const bf16x8*)(sm + row * 256 + col);
    *(bf16x8*)(C + (size_t)(mBase + row) * NN + nBase + colL) = v;
  }
#undef STGA
#undef STGB
#undef LDA
#undef LDB
#undef MFMAQ
#undef BAR
#undef VMC
}

// ---- scan phase 1: per-chunk aggregate, linear domain, 4 ch/thread --------
// agg layout: [channel][chunk] (channel = b*DD + d), values in LOG domain.
// 2-row-deep prefetch rotation keeps ~6 loads in flight per wave.
__global__ __launch_bounds__(256) void k_scan1(const bf16* __restrict__ hW,
                                               float2* __restrict__ agg) {
  const int d0 = threadIdx.x * 4;
  const int b = blockIdx.y, c = blockIdx.z;
  const bf16* p = hW + (size_t)(b * SS + c * CLEN) * NN + d0;
  float Fp[4] = {1.f, 1.f, 1.f, 1.f};
  float v[4] = {0.f, 0.f, 0.f, 0.f};
  bf16x4 hA = *(const bf16x4*)(p);
  bf16x4 fA = *(const bf16x4*)(p + DD);
  bf16x4 iA = *(const bf16x4*)(p + 2 * DD);
  const bf16* p1 = p + NN;
  bf16x4 hB = *(const bf16x4*)(p1);
  bf16x4 fB = *(const bf16x4*)(p1 + DD);
  bf16x4 iB = *(const bf16x4*)(p1 + 2 * DD);
  p += 2 * NN;
#pragma unroll 2
  for (int j = 0; j < CLEN - 2; ++j) {
    bf16x4 hn = *(const bf16x4*)(p);
    bf16x4 fn = *(const bf16x4*)(p + DD);
    bf16x4 in2 = *(const bf16x4*)(p + 2 * DD);
    p += NN;
#pragma unroll
    for (int e = 0; e < 4; ++e) {
      float F, IG;
      gate2((float)hA[e], (float)fA[e], (float)iA[e], F, IG);
      v[e] = fmaf(v[e], F, IG);
      Fp[e] *= F;
    }
    hA = hB; fA = fB; iA = iB;
    hB = hn; fB = fn; iB = in2;
  }
#pragma unroll
  for (int e = 0; e < 4; ++e) {  // row CLEN-2
    float F, IG;
    gate2((float)hA[e], (float)fA[e], (float)iA[e], F, IG);
    v[e] = fmaf(v[e], F, IG);
    Fp[e] *= F;
  }
#pragma unroll
  for (int e = 0; e < 4; ++e) {  // row CLEN-1
    float F, IG;
    gate2((float)hB[e], (float)fB[e], (float)iB[e], F, IG);
    v[e] = fmaf(v[e], F, IG);
    Fp[e] *= F;
  }
  const size_t ch = (size_t)b * DD + d0;
#pragma unroll
  for (int e = 0; e < 4; ++e)
    agg[(ch + e) * CHUNKS + c] =
        make_float2(__logf(fmaxf(Fp[e], 1e-37f)), __logf(fmaxf(v[e], 1e-37f)));
}

// ---- scan phase 2: wave-parallel exclusive scan over chunks (log domain) --
// One wave per channel; lane holds 4 chunk aggregates; shfl tree scan.
__global__ __launch_bounds__(256) void k_scan2(const float2* __restrict__ agg,
                                               float2* __restrict__ pre) {
  const int ch = blockIdx.x * 4 + (threadIdx.x >> 6);
  const int lane = threadIdx.x & 63;
  const float4* src = (const float4*)(agg + (size_t)ch * CHUNKS);
  float4 v0 = src[lane * 2];      // chunks 4*lane, 4*lane+1
  float4 v1 = src[lane * 2 + 1];  // chunks 4*lane+2, 4*lane+3
  // lane-local fold
  float A = v0.x, V = v0.y;
  comb(A, V, v0.z, v0.w);
  comb(A, V, v1.x, v1.y);
  comb(A, V, v1.z, v1.w);
  // inclusive wave scan of lane aggregates
#pragma unroll
  for (int off = 1; off < 64; off <<= 1) {
    float Ao = __shfl_up(A, off);
    float Vo = __shfl_up(V, off);
    if (lane >= off) {
      V = laddexp(Vo + A, V);
      A = Ao + A;
    }
  }
  // exclusive lane prefix
  float exA = __shfl_up(A, 1);
  float exV = __shfl_up(V, 1);
  if (lane == 0) { exA = 0.f; exV = -1e30f; }
  // produce exclusive per-chunk prefixes
  float4 o0, o1;
  o0.x = exA; o0.y = exV;
  comb(exA, exV, v0.x, v0.y);
  o0.z = exA; o0.w = exV;
  comb(exA, exV, v0.z, v0.w);
  o1.x = exA; o1.y = exV;
  comb(exA, exV, v1.x, v1.y);
  o1.z = exA; o1.w = exV;
  float4* dst = (float4*)(pre + (size_t)ch * CHUNKS);
  dst[lane * 2] = o0;
  dst[lane * 2 + 1] = o1;
}

// ---- scan phase 3: re-run chunk in linear domain; out IS the state --------
__global__ __launch_bounds__(256) void k_scan3(const bf16* __restrict__ hW,
                                               const float2* __restrict__ pre,
                                               float* __restrict__ out) {
  const int d0 = threadIdx.x * 4;
  const int b = blockIdx.y, c = blockIdx.z;
  const bf16* p = hW + (size_t)(b * SS + c * CLEN) * NN + d0;
  float* o = out + (size_t)(b * SS + c * CLEN) * DD + d0;
  const size_t ch = (size_t)b * DD + d0;
  float v[4];
#pragma unroll
  for (int e = 0; e < 4; ++e)
    v[e] = __expf(pre[(ch + e) * CHUNKS + c].y);  // exp(-1e30) = 0 for c=0
  bf16x4 hA = *(const bf16x4*)(p);
  bf16x4 fA = *(const bf16x4*)(p + DD);
  bf16x4 iA = *(const bf16x4*)(p + 2 * DD);
  const bf16* p1 = p + NN;
  bf16x4 hB = *(const bf16x4*)(p1);
  bf16x4 fB = *(const bf16x4*)(p1 + DD);
  bf16x4 iB = *(const bf16x4*)(p1 + 2 * DD);
  p += 2 * NN;
#pragma unroll 2
  for (int j = 0; j < CLEN - 2; ++j) {
    bf16x4 hn = *(const bf16x4*)(p);
    bf16x4 fn = *(const bf16x4*)(p + DD);
    bf16x4 in2 = *(const bf16x4*)(p + 2 * DD);
    p += NN;
    float4 ov;
#pragma unroll
    for (int e = 0; e < 4; ++e) {
      float F, IG;
      gate2((float)hA[e], (float)fA[e], (float)iA[e], F, IG);
      v[e] = fmaf(v[e], F, IG);
    }
    ov.x = v[0]; ov.y = v[1]; ov.z = v[2]; ov.w = v[3];
    *(float4*)o = ov;
    o += DD;
    hA = hB; fA = fB; iA = iB;
    hB = hn; fB = fn; iB = in2;
  }
  {  // row CLEN-2
    float4 ov;
#pragma unroll
    for (int e = 0; e < 4; ++e) {
      float F, IG;
      gate2((float)hA[e], (float)fA[e], (float)iA[e], F, IG);
      v[e] = fmaf(v[e], F, IG);
    }
    ov.x = v[0]; ov.y = v[1]; ov.z = v[2]; ov.w = v[3];
    *(float4*)o = ov;
    o += DD;
  }
  {  // row CLEN-1
    float4 ov;
#pragma unroll
    for (int e = 0; e < 4; ++e) {
      float F, IG;
      gate2((float)hB[e], (float)fB[e], (float)iB[e], F, IG);
      v[e] = fmaf(v[e], F, IG);
    }
    ov.x = v[0]; ov.y = v[1]; ov.z = v[2]; ov.w = v[3];
    *(float4*)o = ov;
  }
}

extern "C" void kernel_launch(void* const* d_in, const int* in_sizes, int n_in,
                              void* d_out, int out_size, void* d_ws,
                              size_t ws_size, hipStream_t stream) {
  const float* x = (const float*)d_in[0];
  const float* W = (const float*)d_in[1];
  float* out = (float*)d_out;
  char* ws = (char*)d_ws;

  // workspace layout: [Wt 6MB][xb 64MB][hW 192MB]; agg/pre (8MB each) overlay
  // the xb region, which is dead after the GEMM completes.
  const size_t wtB = (size_t)NN * KK * 2;   //  6,291,456
  const size_t xbB = (size_t)MM * KK * 2;   // 67,108,864
  const size_t aggB = (size_t)CHUNKS * NCH * sizeof(float2);  // 8 MiB
  bf16* Wt = (bf16*)ws;
  bf16* xb = (bf16*)(ws + wtB);
  bf16* hW = (bf16*)(ws + wtB + xbB);
  float2* agg = (float2*)(ws + wtB);          // overlays xb (dead post-GEMM)
  float2* pre = (float2*)(ws + wtB + aggB);

  k_cvt_wt<<<dim3(NN / 32, KK / 32), dim3(32, 8), 0, stream>>>(W, Wt);
  k_cvt_x<<<dim3(MM * KK / 4 / 256), dim3(256), 0, stream>>>((const float4*)x,
                                                             (bf16x4*)xb);
  k_gemm<<<dim3((NN / 256) * (MM / 256)), 512, 0, stream>>>(xb, Wt, hW);
  k_scan1<<<dim3(1, BB, CHUNKS), 256, 0, stream>>>(hW, agg);
  k_scan2<<<dim3(NCH / 4), 256, 0, stream>>>(agg, pre);
  k_scan3<<<dim3(1, BB, CHUNKS), 256, 0, stream>>>(hW, pre, out);
}